// Round 5
// baseline (43748.605 us; speedup 1.0000x reference)
//
#include <hip/hip_runtime.h>
#include <hip/hip_bf16.h>

// TrainerRNN: 10-layer GRU (T=2048, IN=384, H=768) + linear head (384).
// ROUND 4: 2-layer pipelining. R3 = 1.83 us/step x 20480 steps (LLC-latency
// bound, VALUBusy 11.8%). Step latency is near its floor (2-3 LLC round
// trips); attack the STEP COUNT instead. Blocks split: group A (128 blocks)
// runs even layer 2p, group B runs odd layer 2p+1 skewed one tick:
//   tick k: A computes (2p, k), B computes (2p+1, k-1).
// 5 phases x 2049 ticks = 10245 device barriers (vs 20480).
// Weights: 2 layers LDS-resident (6 units x 18 KB = 110.6 KB/block, 1
// block/CU, 256 co-resident -> barrier safe). Activations rotate over 3
// buffers buf[l%3] (phase p writes 2p%3,(2p+1)%3; reads (2p-1)%3; disjoint).
// All cross-block data via RELAXED AGENT sc1 atomics (R3's fence-free
// coherence: L2 never caches these lines). B's gi source is written
// concurrently by A -> B reads gi AFTER the barrier wait (no shadow
// prefetch for B); A's gi source is prior-phase/x -> A keeps shadow prefetch.

#define T_SEQ 2048
#define H_DIM 768
#define IN0   384
#define G3    2304
#define NPHASE 5
#define NBLK  256
#define HALF  128
#define NTHR  192       // 3 waves; 2 units per wave; 6 units per block
#define NOUT  384
#define CTR_STRIDE 32   // counters 128 B apart

__device__ __forceinline__ float sigm(float x) { return 1.0f / (1.0f + __expf(-x)); }

__device__ __forceinline__ float ldg_dev(const float* p) {
    return __hip_atomic_load(p, __ATOMIC_RELAXED, __HIP_MEMORY_SCOPE_AGENT);
}
__device__ __forceinline__ void stg_dev(float* p, float v) {
    __hip_atomic_store(p, v, __ATOMIC_RELAXED, __HIP_MEMORY_SCOPE_AGENT);
}

extern "C" __global__ __launch_bounds__(NTHR, 1) void gru_pair(
    const float* __restrict__ x,
    const float* __restrict__ wih0,
    const float* __restrict__ whh0,
    const float* __restrict__ bih0,
    const float* __restrict__ bhh0,
    const float* __restrict__ wihS,
    const float* __restrict__ whhS,
    const float* __restrict__ bihS,
    const float* __restrict__ bhhS,
    float* __restrict__ b0, float* __restrict__ b1, float* __restrict__ b2,
    unsigned int* __restrict__ ctr)
{
    __shared__ float lds[6 * 4608];        // 110.6 KB

    const int tid  = threadIdx.x;
    const int lane = tid & 63;
    const int wv   = tid >> 6;             // 0..2
    const int bid  = blockIdx.x;
    const bool isA = (bid < HALF);
    const int gb   = isA ? bid : bid - HALF;   // group-local block id
    float* bufs[3] = { b0, b1, b2 };
    unsigned int gstep = 0;

    for (int p = 0; p < NPHASE; ++p) {
        const int layer = 2 * p + (isA ? 0 : 1);
        const int Din   = (layer == 0) ? IN0 : H_DIM;
        const float* wih = (layer == 0) ? wih0 : wihS + (size_t)(layer - 1) * G3 * H_DIM;
        const float* whh = (layer == 0) ? whh0 : whhS + (size_t)(layer - 1) * G3 * H_DIM;
        const float* bih = (layer == 0) ? bih0 : bihS + (size_t)(layer - 1) * G3;
        const float* bhh = (layer == 0) ? bhh0 : bhhS + (size_t)(layer - 1) * G3;
        float*       yc = bufs[layer % 3];                       // my layer's h
        const float* yg = (layer == 0) ? x : bufs[(layer - 1) % 3]; // gi source

        const int j0 = gb * 6 + wv * 2;    // first of my 2 units
        const int ustride = 3 * Din + 3 * H_DIM;
        float* L = lds + (wv * 2) * ustride;

        // ---- stage 2 units' weight rows into LDS ----
        for (int u = 0; u < 2; ++u) {
            for (int g = 0; g < 3; ++g) {
                const float4* src = (const float4*)(wih + (size_t)(j0 + u + g * H_DIM) * Din);
                float4* dst = (float4*)(L + u * ustride + g * Din);
                for (int k = lane; k < Din / 4; k += 64) dst[k] = src[k];
            }
            for (int g = 0; g < 3; ++g) {
                const float4* src = (const float4*)(whh + (size_t)(j0 + u + g * H_DIM) * H_DIM);
                float4* dst = (float4*)(L + u * ustride + 3 * Din + g * H_DIM);
                for (int k = lane; k < H_DIM / 4; k += 64) dst[k] = src[k];
            }
        }
        float bir[2], biz[2], bin_[2], bhr[2], bhz[2], bhn[2];
        for (int u = 0; u < 2; ++u) {
            bir[u] = bih[j0 + u];        biz[u] = bih[j0 + u + 768];
            bin_[u] = bih[j0 + u + 1536];
            bhr[u] = bhh[j0 + u];        bhz[u] = bhh[j0 + u + 768];
            bhn[u] = bhh[j0 + u + 1536];
        }
        __syncthreads();

        const float *Lr[2], *Lz[2], *Ln[2], *Hr[2], *Hz[2], *Hn[2];
        for (int u = 0; u < 2; ++u) {
            const float* B = L + u * ustride;
            Lr[u] = B;            Lz[u] = B + Din;       Ln[u] = B + 2 * Din;
            Hr[u] = B + 3 * Din;  Hz[u] = Hr[u] + H_DIM; Hn[u] = Hz[u] + H_DIM;
        }

        // ---- A: prefetch gi partials for t=0 (source fully written) ----
        float pir[2] = {0.f, 0.f}, piz[2] = {0.f, 0.f}, pin_[2] = {0.f, 0.f};
        if (isA) {
            if (layer == 0) {
#pragma unroll
                for (int kk = 0; kk < IN0 / 64; ++kk) {
                    const int k = lane + kk * 64;
                    const float xv = x[k];
                    pir[0] += xv * Lr[0][k]; pir[1] += xv * Lr[1][k];
                    piz[0] += xv * Lz[0][k]; piz[1] += xv * Lz[1][k];
                    pin_[0] += xv * Ln[0][k]; pin_[1] += xv * Ln[1][k];
                }
            } else {
#pragma unroll
                for (int kk = 0; kk < 12; ++kk) {
                    const int k = lane + kk * 64;
                    const float xv = ldg_dev(yg + k);
                    pir[0] += xv * Lr[0][k]; pir[1] += xv * Lr[1][k];
                    piz[0] += xv * Lz[0][k]; piz[1] += xv * Lz[1][k];
                    pin_[0] += xv * Ln[0][k]; pin_[1] += xv * Ln[1][k];
                }
            }
        }

        for (int tick = 0; tick <= T_SEQ; ++tick) {
            const bool act = isA ? (tick < T_SEQ) : (tick >= 1);
            const int  t   = isA ? tick : (tick - 1);

            if (act) {
                float gir[2], giz[2], gin[2];
                if (isA) {
                    gir[0] = pir[0]; gir[1] = pir[1];
                    giz[0] = piz[0]; giz[1] = piz[1];
                    gin[0] = pin_[0]; gin[1] = pin_[1];
                } else {
                    gir[0] = gir[1] = giz[0] = giz[1] = gin[0] = gin[1] = 0.f;
                    const float* xr = yg + (size_t)t * H_DIM;   // row t: published tick t (<= tick-1)
#pragma unroll
                    for (int kk = 0; kk < 12; ++kk) {
                        const int k = lane + kk * 64;
                        const float xv = ldg_dev(xr + k);
                        gir[0] += xv * Lr[0][k]; gir[1] += xv * Lr[1][k];
                        giz[0] += xv * Lz[0][k]; giz[1] += xv * Lz[1][k];
                        gin[0] += xv * Ln[0][k]; gin[1] += xv * Ln[1][k];
                    }
                }

                float ahr[2] = {0.f, 0.f}, ahz[2] = {0.f, 0.f}, ahn[2] = {0.f, 0.f};
                float hprev[2] = {0.f, 0.f};
                if (t > 0) {
                    const float* hr = yc + (size_t)(t - 1) * H_DIM;
                    hprev[0] = ldg_dev(hr + j0);
                    hprev[1] = ldg_dev(hr + j0 + 1);
#pragma unroll
                    for (int kk = 0; kk < 12; ++kk) {
                        const int k = lane + kk * 64;
                        const float hv = ldg_dev(hr + k);
                        ahr[0] += hv * Hr[0][k]; ahr[1] += hv * Hr[1][k];
                        ahz[0] += hv * Hz[0][k]; ahz[1] += hv * Hz[1][k];
                        ahn[0] += hv * Hn[0][k]; ahn[1] += hv * Hn[1][k];
                    }
                }

                float s0 = gir[0] + ahr[0], s1 = giz[0] + ahz[0], s2 = gin[0], s3 = ahn[0];
                float s4 = gir[1] + ahr[1], s5 = giz[1] + ahz[1], s6 = gin[1], s7 = ahn[1];
#pragma unroll
                for (int off = 32; off > 0; off >>= 1) {
                    s0 += __shfl_xor(s0, off, 64); s1 += __shfl_xor(s1, off, 64);
                    s2 += __shfl_xor(s2, off, 64); s3 += __shfl_xor(s3, off, 64);
                    s4 += __shfl_xor(s4, off, 64); s5 += __shfl_xor(s5, off, 64);
                    s6 += __shfl_xor(s6, off, 64); s7 += __shfl_xor(s7, off, 64);
                }

                if (lane == 0) {
                    const float r0 = sigm(s0 + bir[0] + bhr[0]);
                    const float z0 = sigm(s1 + biz[0] + bhz[0]);
                    const float n0 = tanhf(s2 + bin_[0] + r0 * (s3 + bhn[0]));
                    stg_dev(&yc[(size_t)t * H_DIM + j0], (1.f - z0) * n0 + z0 * hprev[0]);
                    const float r1 = sigm(s4 + bir[1] + bhr[1]);
                    const float z1 = sigm(s5 + biz[1] + bhz[1]);
                    const float n1 = tanhf(s6 + bin_[1] + r1 * (s7 + bhn[1]));
                    stg_dev(&yc[(size_t)t * H_DIM + j0 + 1], (1.f - z1) * n1 + z1 * hprev[1]);
                }
            }

            // ---- arrive (syncthreads drains sc1 stores via vmcnt(0)) ----
            __syncthreads();
            ++gstep;
            if (tid == 0)
                __hip_atomic_fetch_add(&ctr[(bid >> 2) * CTR_STRIDE], 1u,
                                       __ATOMIC_RELAXED, __HIP_MEMORY_SCOPE_AGENT);

            // ---- A: shadow-prefetch gi for next tick ----
            if (isA && (tick + 1) < T_SEQ) {
                const int tn = tick + 1;
                pir[0] = pir[1] = piz[0] = piz[1] = pin_[0] = pin_[1] = 0.f;
                if (layer == 0) {
                    const float* xr = x + (size_t)tn * IN0;
#pragma unroll
                    for (int kk = 0; kk < IN0 / 64; ++kk) {
                        const int k = lane + kk * 64;
                        const float xv = xr[k];
                        pir[0] += xv * Lr[0][k]; pir[1] += xv * Lr[1][k];
                        piz[0] += xv * Lz[0][k]; piz[1] += xv * Lz[1][k];
                        pin_[0] += xv * Ln[0][k]; pin_[1] += xv * Ln[1][k];
                    }
                } else {
                    const float* xr = yg + (size_t)tn * H_DIM;
#pragma unroll
                    for (int kk = 0; kk < 12; ++kk) {
                        const int k = lane + kk * 64;
                        const float xv = ldg_dev(xr + k);
                        pir[0] += xv * Lr[0][k]; pir[1] += xv * Lr[1][k];
                        piz[0] += xv * Lz[0][k]; piz[1] += xv * Lz[1][k];
                        pin_[0] += xv * Ln[0][k]; pin_[1] += xv * Ln[1][k];
                    }
                }
            }

            // ---- wait: wave 0 scans 64 group counters ----
            if (wv == 0) {
                const unsigned int tgt = 4u * gstep;
                for (;;) {
                    const unsigned int v = __hip_atomic_load(
                        &ctr[lane * CTR_STRIDE],
                        __ATOMIC_RELAXED, __HIP_MEMORY_SCOPE_AGENT);
                    if (__all(v >= tgt)) break;
                    __builtin_amdgcn_s_sleep(1);
                }
            }
            __syncthreads();
        }
    }
}

extern "C" __global__ __launch_bounds__(NOUT, 1) void fc_head(
    const float* __restrict__ h,
    const float* __restrict__ fw,
    const float* __restrict__ fb,
    float* __restrict__ out)
{
    __shared__ float hs[H_DIM];
    const int t = blockIdx.x;
    const float* hr = h + (size_t)t * H_DIM;
    for (int k = threadIdx.x; k < H_DIM; k += NOUT) hs[k] = hr[k];
    __syncthreads();

    const int o = threadIdx.x;
    float acc = fb[o];
    const float* wr = fw + (size_t)o * H_DIM;
#pragma unroll 8
    for (int k = 0; k < H_DIM; ++k) acc += hs[k] * wr[k];
    out[(size_t)t * NOUT + o] = acc;
}

extern "C" void kernel_launch(void* const* d_in, const int* in_sizes, int n_in,
                              void* d_out, int out_size, void* d_ws, size_t ws_size,
                              hipStream_t stream)
{
    const float* x    = (const float*)d_in[0];
    const float* wih0 = (const float*)d_in[1];
    const float* whh0 = (const float*)d_in[2];
    const float* bih0 = (const float*)d_in[3];
    const float* bhh0 = (const float*)d_in[4];
    const float* wihS = (const float*)d_in[5];
    const float* whhS = (const float*)d_in[6];
    const float* bihS = (const float*)d_in[7];
    const float* bhhS = (const float*)d_in[8];
    const float* fcw  = (const float*)d_in[9];
    const float* fcb  = (const float*)d_in[10];

    char* ws = (char*)d_ws;
    unsigned int* ctr = (unsigned int*)ws;          // 64 padded group counters
    float* b0 = (float*)(ws + 65536);               // 3 x [2048,768] fp32
    float* b1 = b0 + (size_t)T_SEQ * H_DIM;
    float* b2 = b1 + (size_t)T_SEQ * H_DIM;

    hipMemsetAsync(ctr, 0, 65536, stream);          // zero counters

    hipLaunchKernelGGL(gru_pair, dim3(NBLK), dim3(NTHR), 0, stream,
                       x, wih0, whh0, bih0, bhh0, wihS, whhS, bihS, bhhS,
                       b0, b1, b2, ctr);

    // layer 9 -> buf[9 % 3] = b0
    hipLaunchKernelGGL(fc_head, dim3(T_SEQ), dim3(NOUT), 0, stream,
                       b0, fcw, fcb, (float*)d_out);
}

// Round 6
// 25747.668 us; speedup vs baseline: 1.6991x; 1.6991x over previous
//
#include <hip/hip_runtime.h>
#include <hip/hip_bf16.h>

// TrainerRNN: 10-layer GRU (T=2048, IN=384, H=768) + linear head (384).
// ROUND 5: fix R4's skew. R4 (B lags 1 tick) put B's gi load on the critical
// path (its source row was published at the immediately preceding barrier ->
// unprefetchable): tick 1.83 -> 3.71 us, erasing the halved tick count.
// Now B lags TWO ticks: iteration m: A computes (2p, m), B computes
// (2p+1, m-2). The gi row consumed at iteration m+1 was published at barrier
// m-1 (visible before iteration m starts) -> BOTH groups prefetch gi in the
// arrive->wait shadow; serial path per tick identical to R3's
// (release -> 12 h-loads -> FMA+reduce -> store -> arrive).
// 5 phases x 2050 ticks = 10250 barriers at ~R3 tick latency.
// Coherence: all cross-block data via RELAXED AGENT sc1 atomics (R3 scheme,
// fence-free; L2 never caches these lines). Barrier: 64 padded LLC group
// counters (4 blocks each, relaxed fetch_add); wave 0 scans (1 load/lane).

#define T_SEQ 2048
#define H_DIM 768
#define IN0   384
#define G3    2304
#define NPHASE 5
#define PHASE_TICKS (T_SEQ + 2)
#define NBLK  256
#define HALF  128
#define NTHR  192       // 3 waves; 2 units per wave; 6 units per block
#define NOUT  384
#define CTR_STRIDE 32   // counters 128 B apart

__device__ __forceinline__ float sigm(float x) { return 1.0f / (1.0f + __expf(-x)); }

__device__ __forceinline__ float ldg_dev(const float* p) {
    return __hip_atomic_load(p, __ATOMIC_RELAXED, __HIP_MEMORY_SCOPE_AGENT);
}
__device__ __forceinline__ void stg_dev(float* p, float v) {
    __hip_atomic_store(p, v, __ATOMIC_RELAXED, __HIP_MEMORY_SCOPE_AGENT);
}

extern "C" __global__ __launch_bounds__(NTHR, 1) void gru_pair(
    const float* __restrict__ x,
    const float* __restrict__ wih0,
    const float* __restrict__ whh0,
    const float* __restrict__ bih0,
    const float* __restrict__ bhh0,
    const float* __restrict__ wihS,
    const float* __restrict__ whhS,
    const float* __restrict__ bihS,
    const float* __restrict__ bhhS,
    float* __restrict__ b0, float* __restrict__ b1, float* __restrict__ b2,
    unsigned int* __restrict__ ctr)
{
    __shared__ float lds[6 * 4608];        // 110.6 KB

    const int tid  = threadIdx.x;
    const int lane = tid & 63;
    const int wv   = tid >> 6;             // 0..2
    const int bid  = blockIdx.x;
    const bool isA = (bid < HALF);
    const int skew = isA ? 0 : 2;
    const int gb   = isA ? bid : bid - HALF;   // group-local block id
    float* bufs[3] = { b0, b1, b2 };
    unsigned int gstep = 0;

    for (int p = 0; p < NPHASE; ++p) {
        const int layer = 2 * p + (isA ? 0 : 1);
        const int Din   = (layer == 0) ? IN0 : H_DIM;
        const float* wih = (layer == 0) ? wih0 : wihS + (size_t)(layer - 1) * G3 * H_DIM;
        const float* whh = (layer == 0) ? whh0 : whhS + (size_t)(layer - 1) * G3 * H_DIM;
        const float* bih = (layer == 0) ? bih0 : bihS + (size_t)(layer - 1) * G3;
        const float* bhh = (layer == 0) ? bhh0 : bhhS + (size_t)(layer - 1) * G3;
        float*       yc = bufs[layer % 3];                          // my layer's h
        const float* yg = (layer == 0) ? x : bufs[(layer - 1) % 3]; // gi source

        const int j0 = gb * 6 + wv * 2;    // first of my 2 units
        const int ustride = 3 * Din + 3 * H_DIM;
        float* L = lds + (wv * 2) * ustride;

        // ---- stage 2 units' weight rows into LDS ----
        for (int u = 0; u < 2; ++u) {
            for (int g = 0; g < 3; ++g) {
                const float4* src = (const float4*)(wih + (size_t)(j0 + u + g * H_DIM) * Din);
                float4* dst = (float4*)(L + u * ustride + g * Din);
                for (int k = lane; k < Din / 4; k += 64) dst[k] = src[k];
            }
            for (int g = 0; g < 3; ++g) {
                const float4* src = (const float4*)(whh + (size_t)(j0 + u + g * H_DIM) * H_DIM);
                float4* dst = (float4*)(L + u * ustride + 3 * Din + g * H_DIM);
                for (int k = lane; k < H_DIM / 4; k += 64) dst[k] = src[k];
            }
        }
        float bir[2], biz[2], bin_[2], bhr[2], bhz[2], bhn[2];
        for (int u = 0; u < 2; ++u) {
            bir[u] = bih[j0 + u];        biz[u] = bih[j0 + u + 768];
            bin_[u] = bih[j0 + u + 1536];
            bhr[u] = bhh[j0 + u];        bhz[u] = bhh[j0 + u + 768];
            bhn[u] = bhh[j0 + u + 1536];
        }
        __syncthreads();

        const float *Lr[2], *Lz[2], *Ln[2], *Hr[2], *Hz[2], *Hn[2];
        for (int u = 0; u < 2; ++u) {
            const float* B = L + u * ustride;
            Lr[u] = B;            Lz[u] = B + Din;       Ln[u] = B + 2 * Din;
            Hr[u] = B + 3 * Din;  Hz[u] = Hr[u] + H_DIM; Hn[u] = Hz[u] + H_DIM;
        }

        // ---- pre-loop gi prefetch for iteration 0 (A only; its source is
        //      x / the fully-written previous-phase buffer) ----
        float pir[2] = {0.f, 0.f}, piz[2] = {0.f, 0.f}, pin_[2] = {0.f, 0.f};
        if (isA) {
            if (layer == 0) {
#pragma unroll
                for (int kk = 0; kk < IN0 / 64; ++kk) {
                    const int k = lane + kk * 64;
                    const float xv = x[k];
                    pir[0] += xv * Lr[0][k]; pir[1] += xv * Lr[1][k];
                    piz[0] += xv * Lz[0][k]; piz[1] += xv * Lz[1][k];
                    pin_[0] += xv * Ln[0][k]; pin_[1] += xv * Ln[1][k];
                }
            } else {
#pragma unroll
                for (int kk = 0; kk < 12; ++kk) {
                    const int k = lane + kk * 64;
                    const float xv = ldg_dev(yg + k);
                    pir[0] += xv * Lr[0][k]; pir[1] += xv * Lr[1][k];
                    piz[0] += xv * Lz[0][k]; piz[1] += xv * Lz[1][k];
                    pin_[0] += xv * Ln[0][k]; pin_[1] += xv * Ln[1][k];
                }
            }
        }

        for (int m = 0; m < PHASE_TICKS; ++m) {
            const int t = m - skew;
            const bool act = (t >= 0) && (t < T_SEQ);

            if (act) {
                float ahr[2] = {0.f, 0.f}, ahz[2] = {0.f, 0.f}, ahn[2] = {0.f, 0.f};
                float hprev[2] = {0.f, 0.f};
                if (t > 0) {
                    const float* hr = yc + (size_t)(t - 1) * H_DIM;
                    hprev[0] = ldg_dev(hr + j0);
                    hprev[1] = ldg_dev(hr + j0 + 1);
#pragma unroll
                    for (int kk = 0; kk < 12; ++kk) {
                        const int k = lane + kk * 64;
                        const float hv = ldg_dev(hr + k);
                        ahr[0] += hv * Hr[0][k]; ahr[1] += hv * Hr[1][k];
                        ahz[0] += hv * Hz[0][k]; ahz[1] += hv * Hz[1][k];
                        ahn[0] += hv * Hn[0][k]; ahn[1] += hv * Hn[1][k];
                    }
                }

                float s0 = pir[0] + ahr[0], s1 = piz[0] + ahz[0], s2 = pin_[0], s3 = ahn[0];
                float s4 = pir[1] + ahr[1], s5 = piz[1] + ahz[1], s6 = pin_[1], s7 = ahn[1];
#pragma unroll
                for (int off = 32; off > 0; off >>= 1) {
                    s0 += __shfl_xor(s0, off, 64); s1 += __shfl_xor(s1, off, 64);
                    s2 += __shfl_xor(s2, off, 64); s3 += __shfl_xor(s3, off, 64);
                    s4 += __shfl_xor(s4, off, 64); s5 += __shfl_xor(s5, off, 64);
                    s6 += __shfl_xor(s6, off, 64); s7 += __shfl_xor(s7, off, 64);
                }

                if (lane == 0) {
                    const float r0 = sigm(s0 + bir[0] + bhr[0]);
                    const float z0 = sigm(s1 + biz[0] + bhz[0]);
                    const float n0 = tanhf(s2 + bin_[0] + r0 * (s3 + bhn[0]));
                    stg_dev(&yc[(size_t)t * H_DIM + j0], (1.f - z0) * n0 + z0 * hprev[0]);
                    const float r1 = sigm(s4 + bir[1] + bhr[1]);
                    const float z1 = sigm(s5 + biz[1] + bhz[1]);
                    const float n1 = tanhf(s6 + bin_[1] + r1 * (s7 + bhn[1]));
                    stg_dev(&yc[(size_t)t * H_DIM + j0 + 1], (1.f - z1) * n1 + z1 * hprev[1]);
                }
            }

            // ---- arrive (syncthreads drains sc1 stores via vmcnt(0)) ----
            __syncthreads();
            ++gstep;
            if (tid == 0)
                __hip_atomic_fetch_add(&ctr[(bid >> 2) * CTR_STRIDE], 1u,
                                       __ATOMIC_RELAXED, __HIP_MEMORY_SCOPE_AGENT);

            // ---- shadow gi prefetch for iteration m+1 (BOTH groups).
            //      A: row m+1 from prev-phase buffer (always safe).
            //      B: row m-1, published at barrier m-1 (completed before
            //      iteration m began) -> safe. ----
            const int tn = m + 1 - skew;
            if (tn >= 0 && tn < T_SEQ) {
                pir[0] = pir[1] = piz[0] = piz[1] = pin_[0] = pin_[1] = 0.f;
                if (layer == 0) {
                    const float* xr = x + (size_t)tn * IN0;
#pragma unroll
                    for (int kk = 0; kk < IN0 / 64; ++kk) {
                        const int k = lane + kk * 64;
                        const float xv = xr[k];
                        pir[0] += xv * Lr[0][k]; pir[1] += xv * Lr[1][k];
                        piz[0] += xv * Lz[0][k]; piz[1] += xv * Lz[1][k];
                        pin_[0] += xv * Ln[0][k]; pin_[1] += xv * Ln[1][k];
                    }
                } else {
                    const float* xr = yg + (size_t)tn * H_DIM;
#pragma unroll
                    for (int kk = 0; kk < 12; ++kk) {
                        const int k = lane + kk * 64;
                        const float xv = ldg_dev(xr + k);
                        pir[0] += xv * Lr[0][k]; pir[1] += xv * Lr[1][k];
                        piz[0] += xv * Lz[0][k]; piz[1] += xv * Lz[1][k];
                        pin_[0] += xv * Ln[0][k]; pin_[1] += xv * Ln[1][k];
                    }
                }
            }

            // ---- wait: wave 0 scans 64 group counters ----
            if (wv == 0) {
                const unsigned int tgt = 4u * gstep;
                for (;;) {
                    const unsigned int v = __hip_atomic_load(
                        &ctr[lane * CTR_STRIDE],
                        __ATOMIC_RELAXED, __HIP_MEMORY_SCOPE_AGENT);
                    if (__all(v >= tgt)) break;
                    __builtin_amdgcn_s_sleep(1);
                }
            }
            __syncthreads();
        }
    }
}

extern "C" __global__ __launch_bounds__(NOUT, 1) void fc_head(
    const float* __restrict__ h,
    const float* __restrict__ fw,
    const float* __restrict__ fb,
    float* __restrict__ out)
{
    __shared__ float hs[H_DIM];
    const int t = blockIdx.x;
    const float* hr = h + (size_t)t * H_DIM;
    for (int k = threadIdx.x; k < H_DIM; k += NOUT) hs[k] = hr[k];
    __syncthreads();

    const int o = threadIdx.x;
    float acc = fb[o];
    const float* wr = fw + (size_t)o * H_DIM;
#pragma unroll 8
    for (int k = 0; k < H_DIM; ++k) acc += hs[k] * wr[k];
    out[(size_t)t * NOUT + o] = acc;
}

extern "C" void kernel_launch(void* const* d_in, const int* in_sizes, int n_in,
                              void* d_out, int out_size, void* d_ws, size_t ws_size,
                              hipStream_t stream)
{
    const float* x    = (const float*)d_in[0];
    const float* wih0 = (const float*)d_in[1];
    const float* whh0 = (const float*)d_in[2];
    const float* bih0 = (const float*)d_in[3];
    const float* bhh0 = (const float*)d_in[4];
    const float* wihS = (const float*)d_in[5];
    const float* whhS = (const float*)d_in[6];
    const float* bihS = (const float*)d_in[7];
    const float* bhhS = (const float*)d_in[8];
    const float* fcw  = (const float*)d_in[9];
    const float* fcb  = (const float*)d_in[10];

    char* ws = (char*)d_ws;
    unsigned int* ctr = (unsigned int*)ws;          // 64 padded group counters
    float* b0 = (float*)(ws + 65536);               // 3 x [2048,768] fp32
    float* b1 = b0 + (size_t)T_SEQ * H_DIM;
    float* b2 = b1 + (size_t)T_SEQ * H_DIM;

    hipMemsetAsync(ctr, 0, 65536, stream);          // zero counters

    hipLaunchKernelGGL(gru_pair, dim3(NBLK), dim3(NTHR), 0, stream,
                       x, wih0, whh0, bih0, bhh0, wihS, whhS, bihS, bhhS,
                       b0, b1, b2, ctr);

    // layer 9 -> buf[9 % 3] = b0
    hipLaunchKernelGGL(fc_head, dim3(T_SEQ), dim3(NOUT), 0, stream,
                       b0, fcw, fcb, (float*)d_out);
}